// Round 1
// baseline (24.067 us; speedup 1.0000x reference)
//
#include <hip/hip_runtime.h>

// Problem shape from setup_inputs(): proposals (16, 32768, 4) f32,
// gt_boxes (16, 64, 5) f32 -> out (16, 32768, 5) f32.
#define BATCH 16
#define NPROP 32768
#define NGT   64
#define BLOCK 256

__global__ __launch_bounds__(BLOCK) void rcnn_match_kernel(
    const float* __restrict__ props,   // (B, N, 4)
    const float* __restrict__ gt,      // (B, M, 5)
    float* __restrict__ out)           // (B, N, 5)
{
    // LDS: per-box [x1, y1, x2, y2, cls, area2, pad, pad] (32B stride, aligned)
    __shared__ float sgt[NGT][8];

    const int blocksPerBatch = NPROP / BLOCK;           // 128
    const int b = blockIdx.x / blocksPerBatch;
    const int n = (blockIdx.x % blocksPerBatch) * BLOCK + threadIdx.x;

    // Stage GT boxes into LDS; encode invalid (cls == -1) as a far-away
    // zero-intersection box with area2 = 1 -> iou = 0. Index differences vs
    // the reference's -1 encoding only occur when the output is -1 anyway.
    if (threadIdx.x < NGT) {
        const float* g = gt + ((size_t)b * NGT + threadIdx.x) * 5;
        float x1 = g[0], y1 = g[1], x2 = g[2], y2 = g[3], c = g[4];
        float a2 = (x2 - x1) * (y2 - y1);
        if (c == -1.0f) { x1 = y1 = x2 = y2 = -1.0e4f; a2 = 1.0f; }
        sgt[threadIdx.x][0] = x1;
        sgt[threadIdx.x][1] = y1;
        sgt[threadIdx.x][2] = x2;
        sgt[threadIdx.x][3] = y2;
        sgt[threadIdx.x][4] = c;
        sgt[threadIdx.x][5] = a2;
    }
    __syncthreads();

    const float4 p = reinterpret_cast<const float4*>(props)[(size_t)b * NPROP + n];
    const float area1 = (p.z - p.x) * (p.w - p.y);

    // Argmax over IoU fractions via cross-multiplication (dens strictly > 0);
    // strict '>' preserves first-occurrence argmax semantics.
    float bestNum = -1.0f;   // acts as iou = -1 so m=0 always wins first
    float bestDen = 1.0f;
    int   besti   = 0;

    #pragma unroll 8
    for (int m = 0; m < NGT; ++m) {
        const float gx1 = sgt[m][0];
        const float gy1 = sgt[m][1];
        const float gx2 = sgt[m][2];
        const float gy2 = sgt[m][3];
        const float a2  = sgt[m][5];

        const float ix1 = fmaxf(p.x, gx1);
        const float iy1 = fmaxf(p.y, gy1);
        const float ix2 = fminf(p.z, gx2);
        const float iy2 = fminf(p.w, gy2);
        const float inter = fmaxf(ix2 - ix1, 0.0f) * fmaxf(iy2 - iy1, 0.0f);
        const float den   = (area1 + a2) - inter;   // numpy order: (a1+a2)-inter

        const bool better = inter * bestDen > bestNum * den;
        bestNum = better ? inter : bestNum;
        bestDen = better ? den   : bestDen;
        besti   = better ? m     : besti;
    }

    // One correctly-rounded division, identical operands/order to numpy.
    const float q = bestNum / bestDen;

    float o0, o1, o2, o3, o4;
    if (q <= 0.5f) {
        o0 = o1 = o2 = o3 = o4 = -1.0f;
    } else if (q < 0.6f) {
        o0 = o1 = o2 = o3 = o4 = -1.0e8f;
    } else {
        o0 = sgt[besti][0];
        o1 = sgt[besti][1];
        o2 = sgt[besti][2];
        o3 = sgt[besti][3];
        o4 = sgt[besti][4];
    }

    float* op = out + ((size_t)b * NPROP + n) * 5;
    op[0] = o0; op[1] = o1; op[2] = o2; op[3] = o3; op[4] = o4;
}

extern "C" void kernel_launch(void* const* d_in, const int* in_sizes, int n_in,
                              void* d_out, int out_size, void* d_ws, size_t ws_size,
                              hipStream_t stream) {
    const float* props = (const float*)d_in[0];
    const float* gt    = (const float*)d_in[1];
    float* out = (float*)d_out;

    const int grid = BATCH * (NPROP / BLOCK);   // 2048 blocks
    rcnn_match_kernel<<<grid, BLOCK, 0, stream>>>(props, gt, out);
}